// Round 12
// baseline (298.031 us; speedup 1.0000x reference)
//
#include <hip/hip_runtime.h>

typedef _Float16 h8 __attribute__((ext_vector_type(8)));
typedef _Float16 h2 __attribute__((ext_vector_type(2)));
typedef float f4 __attribute__((ext_vector_type(4)));

#define NHEADS 6
#define LOGMAX 4.6051701859880914f   // ln(100)
#define LOG2E  1.4426950408889634f

// kept position j (0..31) -> row index in window (0..63); kept iff (r+c) even
__device__ __forceinline__ int S_of(int j) { return ((j >> 2) << 3) + ((j & 3) << 1) + ((j >> 2) & 1); }
// complement (masked) position
__device__ __forceinline__ int SC_of(int j) { return ((j >> 2) << 3) + ((j & 3) << 1) + (1 - ((j >> 2) & 1)); }

// 16-lane (DPP row) reductions on the VALU pipe.
template <int CTRL>
__device__ __forceinline__ float dpp_mov(float x) {
    return __builtin_bit_cast(float,
        __builtin_amdgcn_update_dpp(0, __builtin_bit_cast(int, x), CTRL, 0xF, 0xF, true));
}
__device__ __forceinline__ float rowsum16(float x) {
    x += dpp_mov<0x121>(x);   // row_ror:1
    x += dpp_mov<0x122>(x);   // row_ror:2
    x += dpp_mov<0x124>(x);   // row_ror:4
    x += dpp_mov<0x128>(x);   // row_ror:8
    return x;
}
__device__ __forceinline__ unsigned pack2(float a, float b) {
    h2 v; v[0] = (_Float16)a; v[1] = (_Float16)b;
    return __builtin_bit_cast(unsigned, v);
}
// single-instruction transcendentals (avoid libm div/sqrt expansions)
__device__ __forceinline__ float fast_exp2(float x) {
    float r; asm("v_exp_f32 %0, %1" : "=v"(r) : "v"(x)); return r;
}
__device__ __forceinline__ float fast_rcp(float x) {
    float r; asm("v_rcp_f32 %0, %1" : "=v"(r) : "v"(x)); return r;
}
__device__ __forceinline__ float fast_rsq(float x) {
    float r; asm("v_rsq_f32 %0, %1" : "=v"(r) : "v"(x)); return r;
}

// ---------------------------------------------------------------------------
// Pack kernel (unchanged from round 10).
// qkvp: [h][nt 0..5][ks 0..5][lane][8]
// projp: [ksblk=h][nt 0..11][lane][8], k-dim pair-interleaved per head block
// b2t:  [h][32][32] = (bias - scale_h - 1) * LOG2E   (constant-shift softmax)
// sl2t: [h] = scale_h * LOG2E
// ---------------------------------------------------------------------------
__global__ void pack_kernel(const float* __restrict__ qkv_w,
                            const float* __restrict__ proj_w,
                            const float* __restrict__ rel_bias_table,
                            const int* __restrict__ rel_pos_index,
                            const float* __restrict__ logit_scale,
                            _Float16* __restrict__ qkvp,
                            _Float16* __restrict__ projp,
                            float* __restrict__ b2t,
                            float* __restrict__ sl2t) {
    int tid = blockIdx.x * 256 + threadIdx.x;
    const int NQ = 6 * 6 * 6 * 64;        // 13824
    const int NP = 6 * 12 * 64;           // 4608
    if (tid < NQ) {
        int l = tid & 63;
        int rest = tid >> 6;
        int ks = rest % 6;
        int nt = (rest / 6) % 6;
        int h = rest / 36;
        int o = (nt >> 1) * 192 + h * 32 + (nt & 1) * 16 + (l & 15);
        int k0 = ks * 32 + (l >> 4) * 8;
        const float* src = qkv_w + o * 192 + k0;
        _Float16* dst = qkvp + tid * 8;
#pragma unroll
        for (int j = 0; j < 8; ++j) dst[j] = (_Float16)src[j];
    } else if (tid < NQ + NP) {
        int t = tid - NQ;
        int l = t & 63;
        int rest = t >> 6;         // 0..71
        int nt = rest % 12;
        int h = rest / 12;         // k-block (head)
        int o = nt * 16 + (l & 15);
        const float* srcrow = proj_w + o * 192 + h * 32;
        _Float16* dst = projp + t * 8;
        int p0 = (l >> 4) * 8;
#pragma unroll
        for (int j = 0; j < 8; ++j) {
            int p = p0 + j;
            dst[j] = (_Float16)srcrow[(p >> 1) + ((p & 1) << 4)];
        }
    } else if (tid < NQ + NP + 6 * 32 * 32) {
        int t = tid - (NQ + NP);
        int h = t >> 10;
        int jr = (t >> 5) & 31;
        int ic = t & 31;
        int rp = rel_pos_index[S_of(jr) * 64 + S_of(ic)];
        float scale = __expf(fminf(logit_scale[h], LOGMAX));
        b2t[t] = (rel_bias_table[rp * NHEADS + h] - scale - 1.0f) * LOG2E;
        if (jr == 0 && ic == 0) sl2t[h] = scale * LOG2E;
    }
}

// ---------------------------------------------------------------------------
// Main fused kernel: 256 thr = 4 waves = 2 windows; wave (w,mh) owns 16 rows.
// Round-12 change: INTRA-WAVE DUAL-PIPE PIPELINE. A-GEMM(h+1) is issued in
// the SAME barrier region as attention(h) (no data dependence) so the
// scheduler overlaps head h+1's weight MFMAs with head h's softmax VALU.
// Evidence: r10 (12 w/CU) == r11 (8 w/CU) == ~218 µs with MFMA 15% / VALU 23%
// busy in DISJOINT phases — the per-wave serial phase chain is the binder.
// Everything else identical to round 10 (best 12-wave config, no spills).
// ---------------------------------------------------------------------------
__global__ __launch_bounds__(256) __attribute__((amdgpu_waves_per_eu(3, 8)))
void cwa_kernel(
    const float* __restrict__ x,
    const _Float16* __restrict__ qkvp,
    const _Float16* __restrict__ projp,
    const float* __restrict__ b2t,
    const float* __restrict__ sl2t,
    const float* __restrict__ qkv_b,
    const float* __restrict__ proj_b,
    float* __restrict__ out) {
    __shared__ __align__(16) _Float16 wbuf[6 * 6 * 64 * 8];   // 36864 B head tile
    __shared__ __align__(16) unsigned knu[2][32][20];         // 5120 B
    __shared__ __align__(16) _Float16 vT[2][32][40];          // 5120 B
    __shared__ __align__(16) unsigned tmpu[4][16][20];        // 5120 B (q/p/O)
    // total 52224 B -> 3 blocks/CU (12 waves)

    const int tid = threadIdx.x;
    const int lane = tid & 63;
    const int wave = tid >> 6;
    const int cl = lane & 15;
    const int g = lane >> 4;
    const int w0 = blockIdx.x * 2;
    const int w = wave >> 1;    // window within block
    const int mh = wave & 1;    // 16-row m-half within window

    // ---- async-stage head h's weight tile: 9 chunks of 1 KB per wave ----
    auto stage = [&](int h) {
        const _Float16* srcb = qkvp + (long)h * (6 * 6 * 64 * 8) + (wave * 9) * 512 + lane * 8;
        _Float16* dstb = &wbuf[(wave * 9) * 512];
#pragma unroll
        for (int c = 0; c < 9; ++c)
            __builtin_amdgcn_global_load_lds(
                (const __attribute__((address_space(1))) unsigned*)(srcb + c * 512),
                (__attribute__((address_space(3))) unsigned*)(dstb + c * 512),
                16, 0, 0);
    };

    stage(0);   // DMA flies under the prologue below

    // ---- masked rows: output = proj_b ----
    {
        int rowi = tid >> 2;   // 0..63  (2 windows x 32 masked rows)
        int sub = tid & 3;
        long base = ((long)(w0 + (rowi >> 5)) * 64 + SC_of(rowi & 31)) * 192;
#pragma unroll
        for (int i = 0; i < 12; ++i) {
            int c4 = i * 4 + sub;
            *(f4*)(out + base + c4 * 4) = *(const f4*)(proj_b + c4 * 4);
        }
    }

    // ---- load this wave's 16 x-rows into A-fragment registers (fp16) ----
    h8 xf[6];
    {
        long xbase = ((long)(w0 + w) * 64 + S_of(mh * 16 + cl)) * 192;
#pragma unroll
        for (int ks = 0; ks < 6; ++ks) {
            f4 u0 = *(const f4*)(x + xbase + ks * 32 + g * 8);
            f4 u1 = *(const f4*)(x + xbase + ks * 32 + g * 8 + 4);
            h8 hv;
            hv[0] = (_Float16)u0[0]; hv[1] = (_Float16)u0[1];
            hv[2] = (_Float16)u0[2]; hv[3] = (_Float16)u0[3];
            hv[4] = (_Float16)u1[0]; hv[5] = (_Float16)u1[1];
            hv[6] = (_Float16)u1[2]; hv[7] = (_Float16)u1[3];
            xf[ks] = hv;
        }
    }

    f4 pacc[12];
#pragma unroll
    for (int nt = 0; nt < 12; ++nt) pacc[nt] = 0.0f;

    f4 acc[6];   // A-GEMM result for the CURRENT head, produced one region early
#pragma unroll
    for (int nt = 0; nt < 6; ++nt) acc[nt] = 0.0f;

    // ---- alpha(0): wbuf[0] landed; A-GEMM(0) ----
    asm volatile("s_waitcnt vmcnt(0)" ::: "memory");
    __builtin_amdgcn_s_barrier();
#pragma unroll
    for (int ks = 0; ks < 6; ++ks)
#pragma unroll
        for (int nt = 0; nt < 6; ++nt) {
            h8 b = *(const h8*)(&wbuf[((nt * 6 + ks) * 64 + lane) * 8]);
            acc[nt] = __builtin_amdgcn_mfma_f32_16x16x32_f16(xf[ks], b, acc[nt], 0, 0, 0);
        }

#pragma unroll 1
    for (int h = 0; h < NHEADS; ++h) {
        // ---- barrier beta(h): all waves done reading wbuf -> safe to refill
        asm volatile("s_waitcnt lgkmcnt(0)" ::: "memory");
        __builtin_amdgcn_s_barrier();
        if (h + 1 < NHEADS) stage(h + 1);   // DMA covered by the epilogue below

        // ---- epilogue(h): consumes acc (registers only; rsq, DPP sums) ----
        float bq0 = qkv_b[h * 32 + cl], bq1 = qkv_b[h * 32 + 16 + cl];
        float bk0 = qkv_b[192 + h * 32 + cl], bk1 = qkv_b[192 + h * 32 + 16 + cl];
        float bv0 = qkv_b[384 + h * 32 + cl], bv1 = qkv_b[384 + h * 32 + 16 + cl];
        unsigned qw[4], kw[4];
        float vv0[4], vv1[4];
#pragma unroll
        for (int r = 0; r < 4; ++r) {
            float t0 = acc[0][r] + bq0, t1 = acc[1][r] + bq1;
            float ss = rowsum16(fmaf(t0, t0, t1 * t1));
            float rs = fast_rsq(fmaxf(ss, 1e-24f));
            qw[r] = pack2(t0 * rs, t1 * rs);
            t0 = acc[2][r] + bk0; t1 = acc[3][r] + bk1;
            ss = rowsum16(fmaf(t0, t0, t1 * t1));
            rs = fast_rsq(fmaxf(ss, 1e-24f));
            kw[r] = pack2(t0 * rs, t1 * rs);
            vv0[r] = acc[4][r] + bv0;
            vv1[r] = acc[5][r] + bv1;
        }
#pragma unroll
        for (int r = 0; r < 4; ++r) {
            int q = g * 4 + r;
            tmpu[wave][q][cl] = qw[r];
            knu[w][mh * 16 + q][cl] = kw[r];
            int kvpos = 2 * q + mh;
            vT[w][cl][kvpos] = (_Float16)vv0[r];
            vT[w][16 + cl][kvpos] = (_Float16)vv1[r];
        }
        // ---- barrier gamma(h): kn/vT visible (vmcnt NOT drained) ----
        asm volatile("s_waitcnt lgkmcnt(0)" ::: "memory");
        __builtin_amdgcn_s_barrier();

        // ==== overlap region: A-GEMM(h+1) [MFMA] + attention(h) [VALU] =====
        if (h + 1 < NHEADS) {
            // alpha(h+1): stage(h+1) DMA landed (covered by epilogue above)
            asm volatile("s_waitcnt vmcnt(0)" ::: "memory");
            __builtin_amdgcn_s_barrier();
#pragma unroll
            for (int nt = 0; nt < 6; ++nt) acc[nt] = 0.0f;
#pragma unroll
            for (int ks = 0; ks < 6; ++ks)
#pragma unroll
                for (int nt = 0; nt < 6; ++nt) {
                    h8 b = *(const h8*)(&wbuf[((nt * 6 + ks) * 64 + lane) * 8]);
                    acc[nt] = __builtin_amdgcn_mfma_f32_16x16x32_f16(xf[ks], b, acc[nt], 0, 0, 0);
                }
        }
        // attention(h): independent of the A-GEMM above -> scheduler
        // interleaves its VALU (exp/fma/DPP) with the MFMA stream.
        {
            h8 aq = *(const h8*)(&tmpu[wave][cl][g * 4]);
            f4 sN[2];
            sN[0] = 0.0f; sN[1] = 0.0f;
#pragma unroll
            for (int nt = 0; nt < 2; ++nt) {
                h8 bk_ = *(const h8*)(&knu[w][nt * 16 + cl][g * 4]);
                sN[nt] = __builtin_amdgcn_mfma_f32_16x16x32_f16(aq, bk_, sN[nt], 0, 0, 0);
            }
            float sl2 = sl2t[h];
            const float* b2row = b2t + h * 1024 + (mh * 16 + g * 4) * 32;
            unsigned pw[4];
            float invr[4];
#pragma unroll
            for (int r = 0; r < 4; ++r) {
                float e0 = fast_exp2(fmaf(sN[0][r], sl2, b2row[r * 32 + cl]));
                float e1 = fast_exp2(fmaf(sN[1][r], sl2, b2row[r * 32 + 16 + cl]));
                invr[r] = rowsum16(e0 + e1);
                pw[r] = pack2(e0, e1);                // unnormalized P
            }
#pragma unroll
            for (int r = 0; r < 4; ++r) {
                invr[r] = fast_rcp(invr[r]);
                tmpu[wave][g * 4 + r][cl] = pw[r];
            }
            h8 ap = *(const h8*)(&tmpu[wave][cl][g * 4]);
            f4 ov[2];
            ov[0] = 0.0f; ov[1] = 0.0f;
#pragma unroll
            for (int nt = 0; nt < 2; ++nt) {
                h8 bv_ = *(const h8*)(&vT[w][nt * 16 + cl][g * 8]);
                ov[nt] = __builtin_amdgcn_mfma_f32_16x16x32_f16(ap, bv_, ov[nt], 0, 0, 0);
            }
            // O_h -> tmpu with deferred 1/sum folded in, then incremental proj
#pragma unroll
            for (int r = 0; r < 4; ++r)
                tmpu[wave][g * 4 + r][cl] = pack2(ov[0][r] * invr[r], ov[1][r] * invr[r]);
            h8 am = *(const h8*)(&tmpu[wave][cl][g * 4]);
            const _Float16* pp_h = projp + (long)h * 12 * 64 * 8;
#pragma unroll
            for (int nt = 0; nt < 12; ++nt) {
                h8 bp = *(const h8*)(pp_h + ((nt * 64 + lane) << 3));
                pacc[nt] = __builtin_amdgcn_mfma_f32_16x16x32_f16(am, bp, pacc[nt], 0, 0, 0);
            }
        }
        // loop: beta(h+1) drains lgkm (wbuf reads of A-GEMM(h+1)) at loop top
    }

    // ================= Final store: out = pacc + proj_b =================
#pragma unroll
    for (int r = 0; r < 4; ++r) {
        long grow = (long)(w0 + w) * 64 + S_of(mh * 16 + g * 4 + r);
        float* po_ = out + grow * 192 + cl;
#pragma unroll
        for (int nt = 0; nt < 12; ++nt)
            po_[nt * 16] = pacc[nt][r] + proj_b[nt * 16 + cl];
    }
}

extern "C" void kernel_launch(void* const* d_in, const int* in_sizes, int n_in,
                              void* d_out, int out_size, void* d_ws, size_t ws_size,
                              hipStream_t stream) {
    const float* x = (const float*)d_in[0];
    const float* qkv_w = (const float*)d_in[1];
    const float* qkv_b = (const float*)d_in[2];
    const float* proj_w = (const float*)d_in[3];
    const float* proj_b = (const float*)d_in[4];
    const float* logit_scale = (const float*)d_in[5];
    const float* rel_bias_table = (const float*)d_in[6];
    const int* rel_pos_index = (const int*)d_in[7];
    float* out = (float*)d_out;

    const int B = in_sizes[0] / (64 * 192);   // number of windows (8192)

    _Float16* qkvp = (_Float16*)d_ws;                 // 13824*8 f16
    _Float16* projp = qkvp + 6 * 6 * 6 * 64 * 8;      // 4608*8 f16
    float* b2t = (float*)(projp + 6 * 12 * 64 * 8);   // 6*32*32 f32
    float* sl2t = b2t + 6 * 32 * 32;                  // 6 f32

    pack_kernel<<<96, 256, 0, stream>>>(qkv_w, proj_w, rel_bias_table, rel_pos_index,
                                        logit_scale, qkvp, projp, b2t, sl2t);
    cwa_kernel<<<B / 2, 256, 0, stream>>>(x, qkvp, projp, b2t, sl2t, qkv_b, proj_b,
                                          out);
}

// Round 13
// 218.554 us; speedup vs baseline: 1.3636x; 1.3636x over previous
//
#include <hip/hip_runtime.h>

typedef _Float16 h8 __attribute__((ext_vector_type(8)));
typedef _Float16 h2 __attribute__((ext_vector_type(2)));
typedef float f4 __attribute__((ext_vector_type(4)));

#define NHEADS 6
#define LOGMAX 4.6051701859880914f   // ln(100)
#define LOG2E  1.4426950408889634f

// kept position j (0..31) -> row index in window (0..63); kept iff (r+c) even
__device__ __forceinline__ int S_of(int j) { return ((j >> 2) << 3) + ((j & 3) << 1) + ((j >> 2) & 1); }
// complement (masked) position
__device__ __forceinline__ int SC_of(int j) { return ((j >> 2) << 3) + ((j & 3) << 1) + (1 - ((j >> 2) & 1)); }

// 16-lane (DPP row) reductions on the VALU pipe.
template <int CTRL>
__device__ __forceinline__ float dpp_mov(float x) {
    return __builtin_bit_cast(float,
        __builtin_amdgcn_update_dpp(0, __builtin_bit_cast(int, x), CTRL, 0xF, 0xF, true));
}
__device__ __forceinline__ float rowsum16(float x) {
    x += dpp_mov<0x121>(x);   // row_ror:1
    x += dpp_mov<0x122>(x);   // row_ror:2
    x += dpp_mov<0x124>(x);   // row_ror:4
    x += dpp_mov<0x128>(x);   // row_ror:8
    return x;
}
__device__ __forceinline__ unsigned pack2(float a, float b) {
    h2 v; v[0] = (_Float16)a; v[1] = (_Float16)b;
    return __builtin_bit_cast(unsigned, v);
}
// single-instruction transcendentals (avoid libm div/sqrt expansions)
__device__ __forceinline__ float fast_exp2(float x) {
    float r; asm("v_exp_f32 %0, %1" : "=v"(r) : "v"(x)); return r;
}
__device__ __forceinline__ float fast_rcp(float x) {
    float r; asm("v_rcp_f32 %0, %1" : "=v"(r) : "v"(x)); return r;
}
__device__ __forceinline__ float fast_rsq(float x) {
    float r; asm("v_rsq_f32 %0, %1" : "=v"(r) : "v"(x)); return r;
}

// ---------------------------------------------------------------------------
// Pack kernel.
// qkvp: [h][nt 0..5][ks 0..5][lane][8]
// projp: [ksblk=h][nt 0..11][lane][8], k-dim pair-interleaved per head block
// b2t:  [h][32][32] = (bias - scale_h - 1) * LOG2E   (constant-shift softmax:
//       logits = cos*scale+bias with |cos|<=1 keeps exp2 args in range)
// sl2t: [h] = scale_h * LOG2E,  scale_h = exp(min(logit_scale,LOGMAX))
// ---------------------------------------------------------------------------
__global__ void pack_kernel(const float* __restrict__ qkv_w,
                            const float* __restrict__ proj_w,
                            const float* __restrict__ rel_bias_table,
                            const int* __restrict__ rel_pos_index,
                            const float* __restrict__ logit_scale,
                            _Float16* __restrict__ qkvp,
                            _Float16* __restrict__ projp,
                            float* __restrict__ b2t,
                            float* __restrict__ sl2t) {
    int tid = blockIdx.x * 256 + threadIdx.x;
    const int NQ = 6 * 6 * 6 * 64;        // 13824
    const int NP = 6 * 12 * 64;           // 4608
    if (tid < NQ) {
        int l = tid & 63;
        int rest = tid >> 6;
        int ks = rest % 6;
        int nt = (rest / 6) % 6;
        int h = rest / 36;
        int o = (nt >> 1) * 192 + h * 32 + (nt & 1) * 16 + (l & 15);
        int k0 = ks * 32 + (l >> 4) * 8;
        const float* src = qkv_w + o * 192 + k0;
        _Float16* dst = qkvp + tid * 8;
#pragma unroll
        for (int j = 0; j < 8; ++j) dst[j] = (_Float16)src[j];
    } else if (tid < NQ + NP) {
        int t = tid - NQ;
        int l = t & 63;
        int rest = t >> 6;         // 0..71
        int nt = rest % 12;
        int h = rest / 12;         // k-block (head)
        int o = nt * 16 + (l & 15);
        const float* srcrow = proj_w + o * 192 + h * 32;
        _Float16* dst = projp + t * 8;
        int p0 = (l >> 4) * 8;
#pragma unroll
        for (int j = 0; j < 8; ++j) {
            int p = p0 + j;
            dst[j] = (_Float16)srcrow[(p >> 1) + ((p & 1) << 4)];
        }
    } else if (tid < NQ + NP + 6 * 32 * 32) {
        int t = tid - (NQ + NP);
        int h = t >> 10;
        int jr = (t >> 5) & 31;
        int ic = t & 31;
        int rp = rel_pos_index[S_of(jr) * 64 + S_of(ic)];
        float scale = __expf(fminf(logit_scale[h], LOGMAX));
        b2t[t] = (rel_bias_table[rp * NHEADS + h] - scale - 1.0f) * LOG2E;
        if (jr == 0 && ic == 0) sl2t[h] = scale * LOG2E;
    }
}

// ---------------------------------------------------------------------------
// Main fused kernel: 256 thr = 4 waves = 2 windows; wave (w,mh) owns 16 rows.
// Round-10 configuration restored verbatim — the proven optimum (218.8 µs):
//  * global_load_lds weight staging, DMA issued at beta and awaited at the
//    NEXT head's alpha (covered by epilogue+gamma+attention — round 12 proved
//    shrinking this coverage to epilogue-only costs ~80 µs of exposed wait);
//  * 3 barriers/head (alpha vmcnt / beta lgkm / gamma lgkm);
//  * VALU-minimal math: v_rsq for L2-norm, constant-shift softmax (no row
//    max; fma+v_exp per element), v_rcp 1/sum deferred past the PV MFMAs;
//  * incremental proj into pacc[12] (AGPRs), one epilogue store;
//  * waves_per_eu(3,8): the only safe pin (4/EU tiers spill — r2/r3/r9).
// Plateau evidence: r10 (M=16, 12 w/CU) == r11 (M=32, 8 w/CU) == ~218 µs;
// r7/r9/r12 (concurrency, barriers, pipelining) all neutral-or-worse.
// ---------------------------------------------------------------------------
__global__ __launch_bounds__(256) __attribute__((amdgpu_waves_per_eu(3, 8)))
void cwa_kernel(
    const float* __restrict__ x,
    const _Float16* __restrict__ qkvp,
    const _Float16* __restrict__ projp,
    const float* __restrict__ b2t,
    const float* __restrict__ sl2t,
    const float* __restrict__ qkv_b,
    const float* __restrict__ proj_b,
    float* __restrict__ out) {
    __shared__ __align__(16) _Float16 wbuf[6 * 6 * 64 * 8];   // 36864 B head tile
    __shared__ __align__(16) unsigned knu[2][32][20];         // 5120 B
    __shared__ __align__(16) _Float16 vT[2][32][40];          // 5120 B
    __shared__ __align__(16) unsigned tmpu[4][16][20];        // 5120 B (q/p/O)
    // total 52224 B -> 3 blocks/CU (12 waves)

    const int tid = threadIdx.x;
    const int lane = tid & 63;
    const int wave = tid >> 6;
    const int cl = lane & 15;
    const int g = lane >> 4;
    const int w0 = blockIdx.x * 2;
    const int w = wave >> 1;    // window within block
    const int mh = wave & 1;    // 16-row m-half within window

    // ---- async-stage head h's weight tile: 9 chunks of 1 KB per wave ----
    auto stage = [&](int h) {
        const _Float16* srcb = qkvp + (long)h * (6 * 6 * 64 * 8) + (wave * 9) * 512 + lane * 8;
        _Float16* dstb = &wbuf[(wave * 9) * 512];
#pragma unroll
        for (int c = 0; c < 9; ++c)
            __builtin_amdgcn_global_load_lds(
                (const __attribute__((address_space(1))) unsigned*)(srcb + c * 512),
                (__attribute__((address_space(3))) unsigned*)(dstb + c * 512),
                16, 0, 0);
    };

    stage(0);   // DMA flies under the prologue below

    // ---- masked rows: output = proj_b ----
    {
        int rowi = tid >> 2;   // 0..63  (2 windows x 32 masked rows)
        int sub = tid & 3;
        long base = ((long)(w0 + (rowi >> 5)) * 64 + SC_of(rowi & 31)) * 192;
#pragma unroll
        for (int i = 0; i < 12; ++i) {
            int c4 = i * 4 + sub;
            *(f4*)(out + base + c4 * 4) = *(const f4*)(proj_b + c4 * 4);
        }
    }

    // ---- load this wave's 16 x-rows into A-fragment registers (fp16) ----
    h8 xf[6];
    {
        long xbase = ((long)(w0 + w) * 64 + S_of(mh * 16 + cl)) * 192;
#pragma unroll
        for (int ks = 0; ks < 6; ++ks) {
            f4 u0 = *(const f4*)(x + xbase + ks * 32 + g * 8);
            f4 u1 = *(const f4*)(x + xbase + ks * 32 + g * 8 + 4);
            h8 hv;
            hv[0] = (_Float16)u0[0]; hv[1] = (_Float16)u0[1];
            hv[2] = (_Float16)u0[2]; hv[3] = (_Float16)u0[3];
            hv[4] = (_Float16)u1[0]; hv[5] = (_Float16)u1[1];
            hv[6] = (_Float16)u1[2]; hv[7] = (_Float16)u1[3];
            xf[ks] = hv;
        }
    }

    f4 pacc[12];
#pragma unroll
    for (int nt = 0; nt < 12; ++nt) pacc[nt] = 0.0f;

#pragma unroll 1
    for (int h = 0; h < NHEADS; ++h) {
        // ---- barrier alpha: everyone's stage DMA for head h has landed ----
        asm volatile("s_waitcnt vmcnt(0)" ::: "memory");
        __builtin_amdgcn_s_barrier();

        // ================= Phase A: qkv GEMM from LDS wbuf ==================
        f4 acc[6];
#pragma unroll
        for (int nt = 0; nt < 6; ++nt) acc[nt] = 0.0f;
#pragma unroll
        for (int ks = 0; ks < 6; ++ks) {
#pragma unroll
            for (int nt = 0; nt < 6; ++nt) {
                h8 b = *(const h8*)(&wbuf[((nt * 6 + ks) * 64 + lane) * 8]);
                acc[nt] = __builtin_amdgcn_mfma_f32_16x16x32_f16(xf[ks], b, acc[nt], 0, 0, 0);
            }
        }
        // ---- barrier beta: all waves done reading wbuf -> safe to overwrite
        asm volatile("s_waitcnt lgkmcnt(0)" ::: "memory");
        __builtin_amdgcn_s_barrier();
        if (h + 1 < NHEADS) stage(h + 1);   // DMA overlaps epilogue + phase B

        // ---- epilogue (registers only; rsq instead of sqrt+div) ----
        float bq0 = qkv_b[h * 32 + cl], bq1 = qkv_b[h * 32 + 16 + cl];
        float bk0 = qkv_b[192 + h * 32 + cl], bk1 = qkv_b[192 + h * 32 + 16 + cl];
        float bv0 = qkv_b[384 + h * 32 + cl], bv1 = qkv_b[384 + h * 32 + 16 + cl];
        unsigned qw[4], kw[4];
        float vv0[4], vv1[4];
#pragma unroll
        for (int r = 0; r < 4; ++r) {
            float t0 = acc[0][r] + bq0, t1 = acc[1][r] + bq1;
            float ss = rowsum16(fmaf(t0, t0, t1 * t1));
            float rs = fast_rsq(fmaxf(ss, 1e-24f));   // == 1/max(sqrt(ss),1e-12)
            qw[r] = pack2(t0 * rs, t1 * rs);
            t0 = acc[2][r] + bk0; t1 = acc[3][r] + bk1;
            ss = rowsum16(fmaf(t0, t0, t1 * t1));
            rs = fast_rsq(fmaxf(ss, 1e-24f));
            kw[r] = pack2(t0 * rs, t1 * rs);
            vv0[r] = acc[4][r] + bv0;
            vv1[r] = acc[5][r] + bv1;
        }
#pragma unroll
        for (int r = 0; r < 4; ++r) {
            int q = g * 4 + r;
            tmpu[wave][q][cl] = qw[r];
            knu[w][mh * 16 + q][cl] = kw[r];
            int kvpos = 2 * q + mh;
            vT[w][cl][kvpos] = (_Float16)vv0[r];
            vT[w][16 + cl][kvpos] = (_Float16)vv1[r];
        }
        // ---- barrier gamma: kn/vT visible; vmcnt NOT drained (DMA in flight)
        asm volatile("s_waitcnt lgkmcnt(0)" ::: "memory");
        __builtin_amdgcn_s_barrier();

        // ================= Phase B: attention + incremental proj ============
        {
            h8 aq = *(const h8*)(&tmpu[wave][cl][g * 4]);
            f4 sN[2];
            sN[0] = 0.0f; sN[1] = 0.0f;
#pragma unroll
            for (int nt = 0; nt < 2; ++nt) {
                h8 bk_ = *(const h8*)(&knu[w][nt * 16 + cl][g * 4]);
                sN[nt] = __builtin_amdgcn_mfma_f32_16x16x32_f16(aq, bk_, sN[nt], 0, 0, 0);
            }
            float sl2 = sl2t[h];
            const float* b2row = b2t + h * 1024 + (mh * 16 + g * 4) * 32;
            unsigned pw[4];
            float invr[4];
#pragma unroll
            for (int r = 0; r < 4; ++r) {
                // e = 2^(s*sl2 + b2) — constant-shift softmax, no row max
                float e0 = fast_exp2(fmaf(sN[0][r], sl2, b2row[r * 32 + cl]));
                float e1 = fast_exp2(fmaf(sN[1][r], sl2, b2row[r * 32 + 16 + cl]));
                invr[r] = rowsum16(e0 + e1);          // raw sum; rcp below
                pw[r] = pack2(e0, e1);                // unnormalized P
            }
#pragma unroll
            for (int r = 0; r < 4; ++r) {
                invr[r] = fast_rcp(invr[r]);
                tmpu[wave][g * 4 + r][cl] = pw[r];
            }
            h8 ap = *(const h8*)(&tmpu[wave][cl][g * 4]);
            f4 ov[2];
            ov[0] = 0.0f; ov[1] = 0.0f;
#pragma unroll
            for (int nt = 0; nt < 2; ++nt) {
                h8 bv_ = *(const h8*)(&vT[w][nt * 16 + cl][g * 8]);
                ov[nt] = __builtin_amdgcn_mfma_f32_16x16x32_f16(ap, bv_, ov[nt], 0, 0, 0);
            }
            // O_h -> tmpu with the deferred 1/sum folded in, then incr. proj
#pragma unroll
            for (int r = 0; r < 4; ++r)
                tmpu[wave][g * 4 + r][cl] = pack2(ov[0][r] * invr[r], ov[1][r] * invr[r]);
            h8 am = *(const h8*)(&tmpu[wave][cl][g * 4]);
            const _Float16* pp_h = projp + (long)h * 12 * 64 * 8;
#pragma unroll
            for (int nt = 0; nt < 12; ++nt) {
                h8 bp = *(const h8*)(pp_h + ((nt * 64 + lane) << 3));
                pacc[nt] = __builtin_amdgcn_mfma_f32_16x16x32_f16(am, bp, pacc[nt], 0, 0, 0);
            }
        }
        // loop: next alpha drains vmcnt (stage h+1) before touching wbuf
    }

    // ================= Final store: out = pacc + proj_b =================
#pragma unroll
    for (int r = 0; r < 4; ++r) {
        long grow = (long)(w0 + w) * 64 + S_of(mh * 16 + g * 4 + r);
        float* po_ = out + grow * 192 + cl;
#pragma unroll
        for (int nt = 0; nt < 12; ++nt)
            po_[nt * 16] = pacc[nt][r] + proj_b[nt * 16 + cl];
    }
}

extern "C" void kernel_launch(void* const* d_in, const int* in_sizes, int n_in,
                              void* d_out, int out_size, void* d_ws, size_t ws_size,
                              hipStream_t stream) {
    const float* x = (const float*)d_in[0];
    const float* qkv_w = (const float*)d_in[1];
    const float* qkv_b = (const float*)d_in[2];
    const float* proj_w = (const float*)d_in[3];
    const float* proj_b = (const float*)d_in[4];
    const float* logit_scale = (const float*)d_in[5];
    const float* rel_bias_table = (const float*)d_in[6];
    const int* rel_pos_index = (const int*)d_in[7];
    float* out = (float*)d_out;

    const int B = in_sizes[0] / (64 * 192);   // number of windows (8192)

    _Float16* qkvp = (_Float16*)d_ws;                 // 13824*8 f16
    _Float16* projp = qkvp + 6 * 6 * 6 * 64 * 8;      // 4608*8 f16
    float* b2t = (float*)(projp + 6 * 12 * 64 * 8);   // 6*32*32 f32
    float* sl2t = b2t + 6 * 32 * 32;                  // 6 f32

    pack_kernel<<<96, 256, 0, stream>>>(qkv_w, proj_w, rel_bias_table, rel_pos_index,
                                        logit_scale, qkvp, projp, b2t, sl2t);
    cwa_kernel<<<B / 2, 256, 0, stream>>>(x, qkvp, projp, b2t, sl2t, qkv_b, proj_b,
                                          out);
}